// Round 1
// baseline (1969.039 us; speedup 1.0000x reference)
//
#include <hip/hip_runtime.h>
#include <cstdint>
#include <cstddef>

#define DEVINL __device__ __forceinline__

// monotone float<->int encoding for atomicMax on signed int
DEVINL int enc_f(float f) { int b = __float_as_int(f); return b ^ ((b >> 31) & 0x7fffffff); }
DEVINL float dec_f(int k) { return __int_as_float(k ^ ((k >> 31) & 0x7fffffff)); }

__global__ __launch_bounds__(256) void fill_i32(int* __restrict__ p, int val, int n) {
  int i = blockIdx.x * 256 + threadIdx.x;
  if (i < n) p[i] = val;
}

// C[N,M] = A[N,K] @ W[K,M] + bias[M].  64x64 tile, TK=16, 4x4 per thread.
__global__ __launch_bounds__(256) void gemm_bias(
    const float* __restrict__ A, const float* __restrict__ W,
    const float* __restrict__ bias, float* __restrict__ C,
    int N, int K, int M) {
  __shared__ float As[16][68];  // +4 pad keeps 16B align, breaks write conflicts
  __shared__ float Bs[16][68];
  int tid = threadIdx.x;
  int row0 = blockIdx.y * 64;
  int col0 = blockIdx.x * 64;
  int tx = tid & 15, ty = tid >> 4;
  float acc[4][4] = {};
  int ar  = tid >> 2;          // 0..63 : A row within tile
  int akq = (tid & 3) * 4;     // 0,4,8,12 : K quad
  int bk  = tid >> 4;          // 0..15 : B k-row
  int bc  = (tid & 15) * 4;    // col quad
  for (int k0 = 0; k0 < K; k0 += 16) {
    float4 av = make_float4(0.f, 0.f, 0.f, 0.f);
    int arow = row0 + ar;
    if (arow < N) av = *(const float4*)(A + (size_t)arow * K + k0 + akq);
    float4 bv = *(const float4*)(W + (size_t)(k0 + bk) * M + col0 + bc);
    __syncthreads();
    As[akq + 0][ar] = av.x; As[akq + 1][ar] = av.y;
    As[akq + 2][ar] = av.z; As[akq + 3][ar] = av.w;
    *(float4*)(&Bs[bk][bc]) = bv;
    __syncthreads();
#pragma unroll
    for (int kk = 0; kk < 16; kk++) {
      float4 a4 = *(const float4*)(&As[kk][ty * 4]);
      float4 b4 = *(const float4*)(&Bs[kk][tx * 4]);
      float aa[4] = {a4.x, a4.y, a4.z, a4.w};
      float bb[4] = {b4.x, b4.y, b4.z, b4.w};
#pragma unroll
      for (int i = 0; i < 4; i++)
#pragma unroll
        for (int j = 0; j < 4; j++) acc[i][j] = fmaf(aa[i], bb[j], acc[i][j]);
    }
  }
  float4 bb4 = *(const float4*)(bias + col0 + tx * 4);
#pragma unroll
  for (int i = 0; i < 4; i++) {
    int row = row0 + ty * 4 + i;
    if (row < N) {
      float4 o;
      o.x = acc[i][0] + bb4.x; o.y = acc[i][1] + bb4.y;
      o.z = acc[i][2] + bb4.z; o.w = acc[i][3] + bb4.w;
      *(float4*)(C + (size_t)row * M + col0 + tx * 4) = o;
    }
  }
}

// one wave per edge: scores[e,h] = dot(q[dst], k[src]+ea*We) * scale; atomicMax into nmax
__global__ __launch_bounds__(256) void edge_scores(
    const float* __restrict__ q, const float* __restrict__ k,
    const float* __restrict__ ea, const float* __restrict__ We,
    const int* __restrict__ src, const int* __restrict__ dst,
    float* __restrict__ sc, int* __restrict__ nmax,
    int E, int h, int lc, float scale) {
  int w = (blockIdx.x * 256 + threadIdx.x) >> 6;
  int lane = threadIdx.x & 63;
  if (w >= E) return;
  int c = 1 << lc;
  int hc = h << lc;
  int s = src[w] + 1, d = dst[w] + 1;
  float eav = ea[w];
  const float* qr = q + (size_t)d * hc;
  const float* kr = k + (size_t)s * hc;
  for (int j0 = 0; j0 < hc; j0 += 64) {
    int idx = j0 + lane;
    float p = qr[idx] * (kr[idx] + eav * We[idx]);
    for (int m = 1; m < c; m <<= 1) p += __shfl_xor(p, m, 64);
    if ((lane & (c - 1)) == 0) {
      int head = idx >> lc;
      float val = p * scale;
      sc[(size_t)w * h + head] = val;
      atomicMax(&nmax[d * h + head], enc_f(val));
    }
  }
}

// one thread per (edge,head): ex = exp(s - max); den += ex
__global__ __launch_bounds__(256) void exp_den(
    float* __restrict__ sc, const int* __restrict__ nmax,
    float* __restrict__ den, const int* __restrict__ dst, int Eh, int h) {
  int i = blockIdx.x * 256 + threadIdx.x;
  if (i >= Eh) return;
  int e = i / h;
  int head = i - e * h;
  int d = dst[e] + 1;
  float m = dec_f(nmax[d * h + head]);
  float ex = __expf(sc[i] - m);
  sc[i] = ex;
  atomicAdd(&den[d * h + head], ex);
}

// one wave per edge: alpha = ex/den; out[dst] += (v[src]+ea*We)*alpha; write alpha
__global__ __launch_bounds__(256) void edge_message(
    const float* __restrict__ v, const float* __restrict__ ea,
    const float* __restrict__ We, const float* __restrict__ ex,
    const float* __restrict__ den, const int* __restrict__ src,
    const int* __restrict__ dst, float* __restrict__ outp,
    float* __restrict__ alpha, int E, int h, int lc) {
  int w = (blockIdx.x * 256 + threadIdx.x) >> 6;
  int lane = threadIdx.x & 63;
  if (w >= E) return;
  int c = 1 << lc;
  int hc = h << lc;
  int s = src[w] + 1, d = dst[w] + 1;
  float eav = ea[w];
  const float* vr = v + (size_t)s * hc;
  float* orow = outp + (size_t)d * hc;
  for (int j0 = 0; j0 < hc; j0 += 64) {
    int idx = j0 + lane;
    int head = idx >> lc;
    float a = ex[(size_t)w * h + head] / (den[d * h + head] + 1e-16f);
    float m = (vr[idx] + eav * We[idx]) * a;
    atomicAdd(&orow[idx], m);
    if ((lane & (c - 1)) == 0) alpha[(size_t)w * h + head] = a;
  }
}

// one wave per node row of 256: LayerNorm + ReLU (in-place OK)
__global__ __launch_bounds__(256) void ln_relu(
    const float* __restrict__ in, const float* __restrict__ g,
    const float* __restrict__ b, float* __restrict__ o, int N) {
  int w = (blockIdx.x * 256 + threadIdx.x) >> 6;
  int lane = threadIdx.x & 63;
  if (w >= N) return;
  float4 x = *(const float4*)(in + (size_t)w * 256 + lane * 4);
  float s = x.x + x.y + x.z + x.w;
  float s2 = x.x * x.x + x.y * x.y + x.z * x.z + x.w * x.w;
  for (int m = 1; m < 64; m <<= 1) { s += __shfl_xor(s, m, 64); s2 += __shfl_xor(s2, m, 64); }
  float mu = s * (1.0f / 256.0f);
  float var = s2 * (1.0f / 256.0f) - mu * mu;
  float inv = rsqrtf(var + 1e-5f);
  float4 gv = *(const float4*)(g + lane * 4);
  float4 bv = *(const float4*)(b + lane * 4);
  float4 y;
  y.x = fmaxf(fmaf((x.x - mu) * inv, gv.x, bv.x), 0.f);
  y.y = fmaxf(fmaf((x.y - mu) * inv, gv.y, bv.y), 0.f);
  y.z = fmaxf(fmaf((x.z - mu) * inv, gv.z, bv.z), 0.f);
  y.w = fmaxf(fmaf((x.w - mu) * inv, gv.w, bv.w), 0.f);
  *(float4*)(o + (size_t)w * 256 + lane * 4) = y;
}

// xr = x + relu(x3); pooled[batch[n]] += xr; cnt[batch[n]] += 1
__global__ __launch_bounds__(256) void resid_pool(
    const float* __restrict__ x, const float* __restrict__ x3,
    const int* __restrict__ batch, float* __restrict__ pooled,
    float* __restrict__ cnt, int N) {
  int i = blockIdx.x * 256 + threadIdx.x;
  if (i >= N * 192) return;
  int n = i / 192;
  int col = i - n * 192;
  float val = x[i] + fmaxf(x3[i], 0.f);
  int b = batch[n];
  atomicAdd(&pooled[b * 192 + col], val);
  if (col == 0) atomicAdd(&cnt[b], 1.0f);
}

// per-graph MLP head: logits = relu(pooled/cnt @ fc1 + b1) @ fc2 + b2
__global__ __launch_bounds__(64) void head_mlp(
    const float* __restrict__ pooled, const float* __restrict__ cnt,
    const float* __restrict__ fc1w, const float* __restrict__ fc1b,
    const float* __restrict__ fc2w, const float* __restrict__ fc2b,
    float* __restrict__ logits) {
  int b = blockIdx.x;
  int t = threadIdx.x;
  __shared__ float p[192];
  __shared__ float hbuf[32];
  float inv = 1.0f / fmaxf(cnt[b], 1.0f);
  for (int i = t; i < 192; i += 64) p[i] = pooled[b * 192 + i] * inv;
  __syncthreads();
  if (t < 32) {
    float acc = fc1b[t];
    for (int i = 0; i < 192; i++) acc = fmaf(p[i], fc1w[i * 32 + t], acc);
    hbuf[t] = fmaxf(acc, 0.f);
  }
  __syncthreads();
  if (t < 2) {
    float acc = fc2b[t];
    for (int j = 0; j < 32; j++) acc = fmaf(hbuf[j], fc2w[j * 2 + t], acc);
    logits[b * 2 + t] = acc;
  }
}

static inline int divup(int a, int b) { return (a + b - 1) / b; }

extern "C" void kernel_launch(void* const* d_in, const int* in_sizes, int n_in,
                              void* d_out, int out_size, void* d_ws, size_t ws_size,
                              hipStream_t stream) {
  const int N = 20000, E = 320000, B = 64;
  const float* x     = (const float*)d_in[0];
  const int*   ei    = (const int*)d_in[1];
  const float* eattr = (const float*)d_in[2];
  const int*   batch = (const int*)d_in[3];
  const int* srcp = ei;        // row 0
  const int* dstp = ei + E;    // row 1

  // per-layer weights: Wq,bq,Wk,bk,Wv,bv,We,Ws,bs starting at 4, 13, 22
  const float* Wq[3]; const float* bq[3]; const float* Wk[3]; const float* bk[3];
  const float* Wv[3]; const float* bv[3]; const float* We[3]; const float* Ws[3];
  const float* bs[3];
  for (int l = 0; l < 3; l++) {
    int base = 4 + l * 9;
    Wq[l] = (const float*)d_in[base + 0]; bq[l] = (const float*)d_in[base + 1];
    Wk[l] = (const float*)d_in[base + 2]; bk[l] = (const float*)d_in[base + 3];
    Wv[l] = (const float*)d_in[base + 4]; bv[l] = (const float*)d_in[base + 5];
    We[l] = (const float*)d_in[base + 6];
    Ws[l] = (const float*)d_in[base + 7]; bs[l] = (const float*)d_in[base + 8];
  }
  const float* g1  = (const float*)d_in[31]; const float* be1 = (const float*)d_in[32];
  const float* g2  = (const float*)d_in[33]; const float* be2 = (const float*)d_in[34];
  const float* fc1w = (const float*)d_in[35]; const float* fc1b = (const float*)d_in[36];
  const float* fc2w = (const float*)d_in[37]; const float* fc2b = (const float*)d_in[38];

  float* out = (float*)d_out;
  float* logits = out;
  float* a1 = out + 128;
  float* a2 = a1 + (size_t)E * 4;
  float* a3 = a2 + (size_t)E * 4;

  // workspace layout (floats)
  float* ws = (float*)d_ws;
  size_t o = 0;
  float* qb = ws + o; o += (size_t)N * 256;
  float* kb = ws + o; o += (size_t)N * 256;
  float* vb = ws + o; o += (size_t)N * 256;
  float* xa = ws + o; o += (size_t)N * 256;   // layer1 out / layer2 in / layer3 out
  float* xb = ws + o; o += (size_t)N * 256;   // layer2 out / layer3 in
  float* sc = ws + o; o += (size_t)E * 6;
  int*   nmax = (int*)(ws + o); o += (size_t)N * 6;
  float* den  = ws + o; o += (size_t)N * 6;
  float* pooled = ws + o; o += (size_t)B * 192;
  float* cnt    = ws + o; o += B;

  dim3 blk(256);

  struct LayerCfg { int K, M, h, lc; float scale; };
  LayerCfg cfg[3] = {
    {192, 256, 4, 6, 0.125f},
    {256, 256, 4, 6, 0.125f},
    {256, 192, 6, 5, 0.1767766952966369f},
  };
  const float* lin_in[3]  = {x, xa, xb};
  float*       lay_out[3] = {xa, xb, xa};
  float*       alpha_out[3] = {a1, a2, a3};

  for (int l = 0; l < 3; l++) {
    int K = cfg[l].K, M = cfg[l].M, h = cfg[l].h, lc = cfg[l].lc;
    dim3 gg(M / 64, divup(N, 64));
    gemm_bias<<<gg, blk, 0, stream>>>(lin_in[l], Wq[l], bq[l], qb, N, K, M);
    gemm_bias<<<gg, blk, 0, stream>>>(lin_in[l], Wk[l], bk[l], kb, N, K, M);
    gemm_bias<<<gg, blk, 0, stream>>>(lin_in[l], Wv[l], bv[l], vb, N, K, M);
    gemm_bias<<<gg, blk, 0, stream>>>(lin_in[l], Ws[l], bs[l], lay_out[l], N, K, M);

    fill_i32<<<divup(N * h, 256), blk, 0, stream>>>(nmax, (int)0x80000000, N * h);
    fill_i32<<<divup(N * h, 256), blk, 0, stream>>>((int*)den, 0, N * h);

    edge_scores<<<divup(E, 4), blk, 0, stream>>>(qb, kb, eattr, We[l], srcp, dstp,
                                                 sc, nmax, E, h, lc, cfg[l].scale);
    exp_den<<<divup(E * h, 256), blk, 0, stream>>>(sc, nmax, den, dstp, E * h, h);
    edge_message<<<divup(E, 4), blk, 0, stream>>>(vb, eattr, We[l], sc, den, srcp, dstp,
                                                  lay_out[l], alpha_out[l], E, h, lc);
    if (l == 0) ln_relu<<<divup(N, 4), blk, 0, stream>>>(xa, g1, be1, xa, N);
    if (l == 1) ln_relu<<<divup(N, 4), blk, 0, stream>>>(xb, g2, be2, xb, N);
  }

  // residual + relu + pooling (pooled and cnt are contiguous: zero both)
  fill_i32<<<divup(B * 192 + B, 256), blk, 0, stream>>>((int*)pooled, 0, B * 192 + B);
  resid_pool<<<divup(N * 192, 256), blk, 0, stream>>>(x, xa, batch, pooled, cnt, N);
  head_mlp<<<B, dim3(64), 0, stream>>>(pooled, cnt, fc1w, fc1b, fc2w, fc2b, logits);
}

// Round 2
// 1086.421 us; speedup vs baseline: 1.8124x; 1.8124x over previous
//
#include <hip/hip_runtime.h>
#include <cstdint>
#include <cstddef>

#define DEVINL __device__ __forceinline__

__global__ __launch_bounds__(256) void fill_i32(int* __restrict__ p, int val, int n) {
  int i = blockIdx.x * 256 + threadIdx.x;
  if (i < n) p[i] = val;
}

// ---------------- counting sort of edges by dst ----------------

__global__ __launch_bounds__(256) void hist_dst(const int* __restrict__ dst,
                                                int* __restrict__ cnt, int E) {
  int e = blockIdx.x * 256 + threadIdx.x;
  if (e < E) atomicAdd(&cnt[dst[e] + 1], 1);  // d = dst+1 in [1, N-1]
}

// single-block exclusive scan over N=20000 bins (1000 threads x 20 elements)
__global__ __launch_bounds__(1024) void scan_hist(const int* __restrict__ cnt,
                                                  int* __restrict__ start,
                                                  int* __restrict__ off, int N) {
  __shared__ int sums[1024];
  const int CH = 20;
  int t = threadIdx.x;
  int base = t * CH;
  int local[CH];
  int tot = 0;
  if (base < N) {
#pragma unroll
    for (int i = 0; i < CH; i++) { local[i] = cnt[base + i]; tot += local[i]; }
  }
  sums[t] = tot;
  __syncthreads();
  for (int d = 1; d < 1024; d <<= 1) {
    int v = (t >= d) ? sums[t - d] : 0;
    __syncthreads();
    sums[t] += v;
    __syncthreads();
  }
  if (base < N) {
    int run = (t == 0) ? 0 : sums[t - 1];
#pragma unroll
    for (int i = 0; i < CH; i++) { start[base + i] = run; off[base + i] = run; run += local[i]; }
    if (base + CH == N) start[N] = run;
  }
}

__global__ __launch_bounds__(256) void scatter_edges(
    const int* __restrict__ src, const int* __restrict__ dst,
    const float* __restrict__ ea, int* __restrict__ off,
    int* __restrict__ src_s, float* __restrict__ ea_s, int* __restrict__ eid_s, int E) {
  int e = blockIdx.x * 256 + threadIdx.x;
  if (e >= E) return;
  int d = dst[e] + 1;
  int pos = atomicAdd(&off[d], 1);
  src_s[pos] = src[e] + 1;
  ea_s[pos] = ea[e];
  eid_s[pos] = e;
}

// ---------------- fused per-dst attention (flash-style, no atomics) -------
// one wave per dst node; edges [start[d], start[d+1]) sorted by dst.
// H heads, LPH = c/4 lanes per head; active lanes = H*LPH (64 or 48).
template <int H, int LPH>
__global__ __launch_bounds__(256) void attn_fused(
    const float* __restrict__ q, const float* __restrict__ k,
    const float* __restrict__ v, const float* __restrict__ We,
    const int* __restrict__ start, const int* __restrict__ src_s,
    const float* __restrict__ ea_s, const int* __restrict__ eid_s,
    float* __restrict__ sc, float* __restrict__ outp,
    float* __restrict__ alpha, int Nn, float scale) {
  const int HC = H * LPH * 4;
  int w = (blockIdx.x * 256 + threadIdx.x) >> 6;
  int lane = threadIdx.x & 63;
  if (w >= Nn) return;
  int b = start[w], e = start[w + 1];
  if (b == e) return;
  bool act = lane < H * LPH;
  int idx = lane * 4;
  int head = lane / LPH;
  float4 q4 = make_float4(0.f, 0.f, 0.f, 0.f), We4 = q4;
  if (act) {
    q4 = *(const float4*)(q + (size_t)w * HC + idx);
    We4 = *(const float4*)(We + idx);
  }
  float m = -INFINITY, l = 0.f;
  float4 acc = make_float4(0.f, 0.f, 0.f, 0.f);
  for (int pos = b; pos < e; pos++) {
    int s = src_s[pos];
    float eav = ea_s[pos];
    float4 k4 = make_float4(0.f, 0.f, 0.f, 0.f);
    float4 v4 = k4;
    if (act) {
      k4 = *(const float4*)(k + (size_t)s * HC + idx);
      v4 = *(const float4*)(v + (size_t)s * HC + idx);
    }
    k4.x = fmaf(eav, We4.x, k4.x); k4.y = fmaf(eav, We4.y, k4.y);
    k4.z = fmaf(eav, We4.z, k4.z); k4.w = fmaf(eav, We4.w, k4.w);
    v4.x = fmaf(eav, We4.x, v4.x); v4.y = fmaf(eav, We4.y, v4.y);
    v4.z = fmaf(eav, We4.z, v4.z); v4.w = fmaf(eav, We4.w, v4.w);
    float p = q4.x * k4.x + q4.y * k4.y + q4.z * k4.z + q4.w * k4.w;
#pragma unroll
    for (int mm = 1; mm < LPH; mm <<= 1) p += __shfl_xor(p, mm, 64);
    float score = p * scale;
    if (act && (lane % LPH) == 0) sc[(size_t)pos * H + head] = score;
    float mn = fmaxf(m, score);
    float f = __expf(m - mn);
    float es = __expf(score - mn);
    l = l * f + es;
    m = mn;
    acc.x = fmaf(acc.x, f, es * v4.x);
    acc.y = fmaf(acc.y, f, es * v4.y);
    acc.z = fmaf(acc.z, f, es * v4.z);
    acc.w = fmaf(acc.w, f, es * v4.w);
  }
  float invl = 1.0f / (l + 1e-16f);
  if (act) {
    float* orow = outp + (size_t)w * HC + idx;
    float4 o = *(float4*)orow;
    o.x += acc.x * invl; o.y += acc.y * invl;
    o.z += acc.z * invl; o.w += acc.w * invl;
    *(float4*)orow = o;
  }
  // alpha writes (scattered by original edge id)
  for (int pos = b; pos < e; pos++) {
    if (act && (lane % LPH) == 0) {
      float sv = sc[(size_t)pos * H + head];
      alpha[(size_t)eid_s[pos] * H + head] = __expf(sv - m) * invl;
    }
  }
}

// ---------------- dense kernels (unchanged from R0) ----------------

__global__ __launch_bounds__(256) void gemm_bias(
    const float* __restrict__ A, const float* __restrict__ W,
    const float* __restrict__ bias, float* __restrict__ C,
    int N, int K, int M) {
  __shared__ float As[16][68];
  __shared__ float Bs[16][68];
  int tid = threadIdx.x;
  int row0 = blockIdx.y * 64;
  int col0 = blockIdx.x * 64;
  int tx = tid & 15, ty = tid >> 4;
  float acc[4][4] = {};
  int ar = tid >> 2;
  int akq = (tid & 3) * 4;
  int bk = tid >> 4;
  int bc = (tid & 15) * 4;
  for (int k0 = 0; k0 < K; k0 += 16) {
    float4 av = make_float4(0.f, 0.f, 0.f, 0.f);
    int arow = row0 + ar;
    if (arow < N) av = *(const float4*)(A + (size_t)arow * K + k0 + akq);
    float4 bv = *(const float4*)(W + (size_t)(k0 + bk) * M + col0 + bc);
    __syncthreads();
    As[akq + 0][ar] = av.x; As[akq + 1][ar] = av.y;
    As[akq + 2][ar] = av.z; As[akq + 3][ar] = av.w;
    *(float4*)(&Bs[bk][bc]) = bv;
    __syncthreads();
#pragma unroll
    for (int kk = 0; kk < 16; kk++) {
      float4 a4 = *(const float4*)(&As[kk][ty * 4]);
      float4 b4 = *(const float4*)(&Bs[kk][tx * 4]);
      float aa[4] = {a4.x, a4.y, a4.z, a4.w};
      float bb[4] = {b4.x, b4.y, b4.z, b4.w};
#pragma unroll
      for (int i = 0; i < 4; i++)
#pragma unroll
        for (int j = 0; j < 4; j++) acc[i][j] = fmaf(aa[i], bb[j], acc[i][j]);
    }
  }
  float4 bb4 = *(const float4*)(bias + col0 + tx * 4);
#pragma unroll
  for (int i = 0; i < 4; i++) {
    int row = row0 + ty * 4 + i;
    if (row < N) {
      float4 o;
      o.x = acc[i][0] + bb4.x; o.y = acc[i][1] + bb4.y;
      o.z = acc[i][2] + bb4.z; o.w = acc[i][3] + bb4.w;
      *(float4*)(C + (size_t)row * M + col0 + tx * 4) = o;
    }
  }
}

__global__ __launch_bounds__(256) void ln_relu(
    const float* __restrict__ in, const float* __restrict__ g,
    const float* __restrict__ b, float* __restrict__ o, int N) {
  int w = (blockIdx.x * 256 + threadIdx.x) >> 6;
  int lane = threadIdx.x & 63;
  if (w >= N) return;
  float4 x = *(const float4*)(in + (size_t)w * 256 + lane * 4);
  float s = x.x + x.y + x.z + x.w;
  float s2 = x.x * x.x + x.y * x.y + x.z * x.z + x.w * x.w;
  for (int m = 1; m < 64; m <<= 1) { s += __shfl_xor(s, m, 64); s2 += __shfl_xor(s2, m, 64); }
  float mu = s * (1.0f / 256.0f);
  float var = s2 * (1.0f / 256.0f) - mu * mu;
  float inv = rsqrtf(var + 1e-5f);
  float4 gv = *(const float4*)(g + lane * 4);
  float4 bv = *(const float4*)(b + lane * 4);
  float4 y;
  y.x = fmaxf(fmaf((x.x - mu) * inv, gv.x, bv.x), 0.f);
  y.y = fmaxf(fmaf((x.y - mu) * inv, gv.y, bv.y), 0.f);
  y.z = fmaxf(fmaf((x.z - mu) * inv, gv.z, bv.z), 0.f);
  y.w = fmaxf(fmaf((x.w - mu) * inv, gv.w, bv.w), 0.f);
  *(float4*)(o + (size_t)w * 256 + lane * 4) = y;
}

__global__ __launch_bounds__(256) void resid_pool(
    const float* __restrict__ x, const float* __restrict__ x3,
    const int* __restrict__ batch, float* __restrict__ pooled,
    float* __restrict__ cnt, int N) {
  int i = blockIdx.x * 256 + threadIdx.x;
  if (i >= N * 192) return;
  int n = i / 192;
  int col = i - n * 192;
  float val = x[i] + fmaxf(x3[i], 0.f);
  int b = batch[n];
  atomicAdd(&pooled[b * 192 + col], val);
  if (col == 0) atomicAdd(&cnt[b], 1.0f);
}

__global__ __launch_bounds__(64) void head_mlp(
    const float* __restrict__ pooled, const float* __restrict__ cnt,
    const float* __restrict__ fc1w, const float* __restrict__ fc1b,
    const float* __restrict__ fc2w, const float* __restrict__ fc2b,
    float* __restrict__ logits) {
  int b = blockIdx.x;
  int t = threadIdx.x;
  __shared__ float p[192];
  __shared__ float hbuf[32];
  float inv = 1.0f / fmaxf(cnt[b], 1.0f);
  for (int i = t; i < 192; i += 64) p[i] = pooled[b * 192 + i] * inv;
  __syncthreads();
  if (t < 32) {
    float acc = fc1b[t];
    for (int i = 0; i < 192; i++) acc = fmaf(p[i], fc1w[i * 32 + t], acc);
    hbuf[t] = fmaxf(acc, 0.f);
  }
  __syncthreads();
  if (t < 2) {
    float acc = fc2b[t];
    for (int j = 0; j < 32; j++) acc = fmaf(hbuf[j], fc2w[j * 2 + t], acc);
    logits[b * 2 + t] = acc;
  }
}

static inline int divup(int a, int b) { return (a + b - 1) / b; }

extern "C" void kernel_launch(void* const* d_in, const int* in_sizes, int n_in,
                              void* d_out, int out_size, void* d_ws, size_t ws_size,
                              hipStream_t stream) {
  const int N = 20000, E = 320000, B = 64;
  const float* x     = (const float*)d_in[0];
  const int*   ei    = (const int*)d_in[1];
  const float* eattr = (const float*)d_in[2];
  const int*   batch = (const int*)d_in[3];
  const int* srcp = ei;
  const int* dstp = ei + E;

  const float* Wq[3]; const float* bq[3]; const float* Wk[3]; const float* bk[3];
  const float* Wv[3]; const float* bv[3]; const float* We[3]; const float* Ws[3];
  const float* bs[3];
  for (int l = 0; l < 3; l++) {
    int base = 4 + l * 9;
    Wq[l] = (const float*)d_in[base + 0]; bq[l] = (const float*)d_in[base + 1];
    Wk[l] = (const float*)d_in[base + 2]; bk[l] = (const float*)d_in[base + 3];
    Wv[l] = (const float*)d_in[base + 4]; bv[l] = (const float*)d_in[base + 5];
    We[l] = (const float*)d_in[base + 6];
    Ws[l] = (const float*)d_in[base + 7]; bs[l] = (const float*)d_in[base + 8];
  }
  const float* g1  = (const float*)d_in[31]; const float* be1 = (const float*)d_in[32];
  const float* g2  = (const float*)d_in[33]; const float* be2 = (const float*)d_in[34];
  const float* fc1w = (const float*)d_in[35]; const float* fc1b = (const float*)d_in[36];
  const float* fc2w = (const float*)d_in[37]; const float* fc2b = (const float*)d_in[38];

  float* out = (float*)d_out;
  float* logits = out;
  float* a1 = out + 128;
  float* a2 = a1 + (size_t)E * 4;
  float* a3 = a2 + (size_t)E * 4;

  float* ws = (float*)d_ws;
  size_t o = 0;
  float* qb = ws + o; o += (size_t)N * 256;
  float* kb = ws + o; o += (size_t)N * 256;
  float* vb = ws + o; o += (size_t)N * 256;
  float* xa = ws + o; o += (size_t)N * 256;
  float* xb = ws + o; o += (size_t)N * 256;
  float* sc = ws + o; o += (size_t)E * 6;
  int*   cntb  = (int*)(ws + o); o += N;      // histogram bins
  int*   startb= (int*)(ws + o); o += N + 1;
  int*   offb  = (int*)(ws + o); o += N + 1;  // running offsets (scatter-consumed)
  int*   src_s = (int*)(ws + o); o += E;
  float* ea_s  = ws + o; o += E;
  int*   eid_s = (int*)(ws + o); o += E;
  float* pooled = ws + o; o += (size_t)B * 192;
  float* cnt    = ws + o; o += B;

  dim3 blk(256);

  // ---- counting sort of edges by dst (once; shared by all 3 layers) ----
  fill_i32<<<divup(N, 256), blk, 0, stream>>>(cntb, 0, N);
  hist_dst<<<divup(E, 256), blk, 0, stream>>>(dstp, cntb, E);
  scan_hist<<<1, dim3(1024), 0, stream>>>(cntb, startb, offb, N);
  scatter_edges<<<divup(E, 256), blk, 0, stream>>>(srcp, dstp, eattr, offb,
                                                  src_s, ea_s, eid_s, E);

  struct LayerCfg { int K, M; float scale; };
  LayerCfg cfg[3] = {
    {192, 256, 0.125f},
    {256, 256, 0.125f},
    {256, 192, 0.1767766952966369f},
  };
  const float* lin_in[3]  = {x, xa, xb};
  float*       lay_out[3] = {xa, xb, xa};
  float*       alpha_out[3] = {a1, a2, a3};

  for (int l = 0; l < 3; l++) {
    int K = cfg[l].K, M = cfg[l].M;
    dim3 gg(M / 64, divup(N, 64));
    gemm_bias<<<gg, blk, 0, stream>>>(lin_in[l], Wq[l], bq[l], qb, N, K, M);
    gemm_bias<<<gg, blk, 0, stream>>>(lin_in[l], Wk[l], bk[l], kb, N, K, M);
    gemm_bias<<<gg, blk, 0, stream>>>(lin_in[l], Wv[l], bv[l], vb, N, K, M);
    gemm_bias<<<gg, blk, 0, stream>>>(lin_in[l], Ws[l], bs[l], lay_out[l], N, K, M);

    dim3 ga(divup(N * 64, 256));
    if (l < 2) {
      attn_fused<4, 16><<<ga, blk, 0, stream>>>(qb, kb, vb, We[l], startb, src_s,
                                                ea_s, eid_s, sc, lay_out[l],
                                                alpha_out[l], N, cfg[l].scale);
    } else {
      attn_fused<6, 8><<<ga, blk, 0, stream>>>(qb, kb, vb, We[l], startb, src_s,
                                               ea_s, eid_s, sc, lay_out[l],
                                               alpha_out[l], N, cfg[l].scale);
    }
    if (l == 0) ln_relu<<<divup(N, 4), blk, 0, stream>>>(xa, g1, be1, xa, N);
    if (l == 1) ln_relu<<<divup(N, 4), blk, 0, stream>>>(xb, g2, be2, xb, N);
  }

  fill_i32<<<divup(B * 192 + B, 256), blk, 0, stream>>>((int*)pooled, 0, B * 192 + B);
  resid_pool<<<divup(N * 192, 256), blk, 0, stream>>>(x, xa, batch, pooled, cnt, N);
  head_mlp<<<B, dim3(64), 0, stream>>>(pooled, cnt, fc1w, fc1b, fc2w, fc2b, logits);
}

// Round 3
// 1023.428 us; speedup vs baseline: 1.9240x; 1.0616x over previous
//
#include <hip/hip_runtime.h>
#include <cstdint>
#include <cstddef>

#define DEVINL __device__ __forceinline__

typedef short s16x8 __attribute__((ext_vector_type(8)));   // 8 bf16 in 4 VGPRs
typedef float f32x4 __attribute__((ext_vector_type(4)));

DEVINL unsigned short f2bf(float f) {
  unsigned u = __float_as_uint(f);
  unsigned r = (u + 0x7FFFu + ((u >> 16) & 1u)) >> 16;
  return (unsigned short)r;
}
DEVINL float bf2f(unsigned short b) { return __uint_as_float(((unsigned)b) << 16); }

__global__ __launch_bounds__(256) void fill_i32(int* __restrict__ p, int val, int n) {
  int i = blockIdx.x * 256 + threadIdx.x;
  if (i < n) p[i] = val;
}

// ---------------- bf16 hi/lo split conversions ----------------

__global__ __launch_bounds__(256) void cvt_split(const float* __restrict__ in,
                                                 unsigned short* __restrict__ hi,
                                                 unsigned short* __restrict__ lo, int n) {
  int i = blockIdx.x * 256 + threadIdx.x;
  if (i >= n) return;
  float f = in[i];
  unsigned short h = f2bf(f);
  float r = f - bf2f(h);
  hi[i] = h;
  lo[i] = f2bf(r);
}

// W[K,M] fp32 -> Wt_hi/lo[M,K] bf16 (transposed for contiguous B fragments)
__global__ __launch_bounds__(256) void cvt_w(const float* __restrict__ W,
                                             unsigned short* __restrict__ Wh,
                                             unsigned short* __restrict__ Wl,
                                             int K, int M) {
  int i = blockIdx.x * 256 + threadIdx.x;
  if (i >= K * M) return;
  int k = i / M, m = i - k * M;
  float f = W[i];
  unsigned short h = f2bf(f);
  float r = f - bf2f(h);
  Wh[(size_t)m * K + k] = h;
  Wl[(size_t)m * K + k] = f2bf(r);
}

// ---------------- fused 4-matrix MFMA GEMM (bf16x3 split precision) -------
// grid: (M/64, divup(N,256), 4).  block 256 = 4 waves stacked on rows.
// out[z][row, col] = A[row,:] @ W[z][:, col] + bias[z][col]
struct GemmArgs {
  const unsigned short* Wh[4];
  const unsigned short* Wl[4];
  const float* bias[4];
  float* out[4];
};

__global__ __launch_bounds__(256) void gemm4_mfma(
    const unsigned short* __restrict__ Ah, const unsigned short* __restrict__ Al,
    GemmArgs args, int N, int K, int M) {
  const unsigned short* Wh = args.Wh[blockIdx.z];
  const unsigned short* Wl = args.Wl[blockIdx.z];
  const float* bias = args.bias[blockIdx.z];
  float* C = args.out[blockIdx.z];
  int wave = threadIdx.x >> 6;
  int lane = threadIdx.x & 63;
  int lrow = lane & 15;
  int quad = lane >> 4;
  int row0 = blockIdx.y * 256 + wave * 64;
  int col0 = blockIdx.x * 64;
  f32x4 acc[4][4] = {};
  s16x8 zero8 = {0, 0, 0, 0, 0, 0, 0, 0};
  for (int k0 = 0; k0 < K; k0 += 32) {
    s16x8 a_h[4], a_l[4], b_h[4], b_l[4];
#pragma unroll
    for (int t = 0; t < 4; t++) {
      int ar = row0 + t * 16 + lrow;
      if (ar < N) {
        size_t aoff = (size_t)ar * K + k0 + quad * 8;
        a_h[t] = *(const s16x8*)(Ah + aoff);
        a_l[t] = *(const s16x8*)(Al + aoff);
      } else {
        a_h[t] = zero8; a_l[t] = zero8;
      }
      int bn = col0 + t * 16 + lrow;                 // always < M (M % 64 == 0)
      size_t boff = (size_t)bn * K + k0 + quad * 8;
      b_h[t] = *(const s16x8*)(Wh + boff);
      b_l[t] = *(const s16x8*)(Wl + boff);
    }
#pragma unroll
    for (int ti = 0; ti < 4; ti++)
#pragma unroll
      for (int tj = 0; tj < 4; tj++) {
        acc[ti][tj] = __builtin_amdgcn_mfma_f32_16x16x32_bf16(a_h[ti], b_h[tj], acc[ti][tj], 0, 0, 0);
        acc[ti][tj] = __builtin_amdgcn_mfma_f32_16x16x32_bf16(a_l[ti], b_h[tj], acc[ti][tj], 0, 0, 0);
        acc[ti][tj] = __builtin_amdgcn_mfma_f32_16x16x32_bf16(a_h[ti], b_l[tj], acc[ti][tj], 0, 0, 0);
      }
  }
  // epilogue: C/D layout col=lane&15, row=quad*4+reg  (m89/m91 verified)
#pragma unroll
  for (int tj = 0; tj < 4; tj++) {
    int col = col0 + tj * 16 + lrow;
    float bv = bias[col];
#pragma unroll
    for (int ti = 0; ti < 4; ti++) {
#pragma unroll
      for (int r = 0; r < 4; r++) {
        int row = row0 + ti * 16 + quad * 4 + r;
        if (row < N) C[(size_t)row * M + col] = acc[ti][tj][r] + bv;
      }
    }
  }
}

// ---------------- counting sort of edges by dst ----------------

__global__ __launch_bounds__(256) void hist_dst(const int* __restrict__ dst,
                                                int* __restrict__ cnt, int E) {
  int e = blockIdx.x * 256 + threadIdx.x;
  if (e < E) atomicAdd(&cnt[dst[e] + 1], 1);
}

__global__ __launch_bounds__(1024) void scan_hist(const int* __restrict__ cnt,
                                                  int* __restrict__ start,
                                                  int* __restrict__ off, int N) {
  __shared__ int sums[1024];
  const int CH = 20;
  int t = threadIdx.x;
  int base = t * CH;
  int local[CH];
  int tot = 0;
  if (base < N) {
#pragma unroll
    for (int i = 0; i < CH; i++) { local[i] = cnt[base + i]; tot += local[i]; }
  }
  sums[t] = tot;
  __syncthreads();
  for (int d = 1; d < 1024; d <<= 1) {
    int v = (t >= d) ? sums[t - d] : 0;
    __syncthreads();
    sums[t] += v;
    __syncthreads();
  }
  if (base < N) {
    int run = (t == 0) ? 0 : sums[t - 1];
#pragma unroll
    for (int i = 0; i < CH; i++) { start[base + i] = run; off[base + i] = run; run += local[i]; }
    if (base + CH == N) start[N] = run;
  }
}

__global__ __launch_bounds__(256) void scatter_edges(
    const int* __restrict__ src, const int* __restrict__ dst,
    const float* __restrict__ ea, int* __restrict__ off,
    int* __restrict__ src_s, float* __restrict__ ea_s, int* __restrict__ eid_s, int E) {
  int e = blockIdx.x * 256 + threadIdx.x;
  if (e >= E) return;
  int d = dst[e] + 1;
  int pos = atomicAdd(&off[d], 1);
  src_s[pos] = src[e] + 1;
  ea_s[pos] = ea[e];
  eid_s[pos] = e;
}

// ---------------- fused per-dst attention (flash-style) ----------------
template <int H, int LPH>
__global__ __launch_bounds__(256) void attn_fused(
    const float* __restrict__ q, const float* __restrict__ k,
    const float* __restrict__ v, const float* __restrict__ We,
    const int* __restrict__ start, const int* __restrict__ src_s,
    const float* __restrict__ ea_s, const int* __restrict__ eid_s,
    float* __restrict__ sc, float* __restrict__ outp,
    float* __restrict__ alpha, int Nn, float scale) {
  const int HC = H * LPH * 4;
  int w = (blockIdx.x * 256 + threadIdx.x) >> 6;
  int lane = threadIdx.x & 63;
  if (w >= Nn) return;
  int b = start[w], e = start[w + 1];
  if (b == e) return;
  bool act = lane < H * LPH;
  int idx = lane * 4;
  int head = lane / LPH;
  float4 q4 = make_float4(0.f, 0.f, 0.f, 0.f), We4 = q4;
  if (act) {
    q4 = *(const float4*)(q + (size_t)w * HC + idx);
    We4 = *(const float4*)(We + idx);
  }
  float m = -INFINITY, l = 0.f;
  float4 acc = make_float4(0.f, 0.f, 0.f, 0.f);
  for (int pos = b; pos < e; pos++) {
    int s = src_s[pos];
    float eav = ea_s[pos];
    float4 k4 = make_float4(0.f, 0.f, 0.f, 0.f);
    float4 v4 = k4;
    if (act) {
      k4 = *(const float4*)(k + (size_t)s * HC + idx);
      v4 = *(const float4*)(v + (size_t)s * HC + idx);
    }
    k4.x = fmaf(eav, We4.x, k4.x); k4.y = fmaf(eav, We4.y, k4.y);
    k4.z = fmaf(eav, We4.z, k4.z); k4.w = fmaf(eav, We4.w, k4.w);
    v4.x = fmaf(eav, We4.x, v4.x); v4.y = fmaf(eav, We4.y, v4.y);
    v4.z = fmaf(eav, We4.z, v4.z); v4.w = fmaf(eav, We4.w, v4.w);
    float p = q4.x * k4.x + q4.y * k4.y + q4.z * k4.z + q4.w * k4.w;
#pragma unroll
    for (int mm = 1; mm < LPH; mm <<= 1) p += __shfl_xor(p, mm, 64);
    float score = p * scale;
    if (act && (lane % LPH) == 0) sc[(size_t)pos * H + head] = score;
    float mn = fmaxf(m, score);
    float f = __expf(m - mn);
    float es = __expf(score - mn);
    l = l * f + es;
    m = mn;
    acc.x = fmaf(acc.x, f, es * v4.x);
    acc.y = fmaf(acc.y, f, es * v4.y);
    acc.z = fmaf(acc.z, f, es * v4.z);
    acc.w = fmaf(acc.w, f, es * v4.w);
  }
  float invl = 1.0f / (l + 1e-16f);
  if (act) {
    float* orow = outp + (size_t)w * HC + idx;
    float4 o = *(float4*)orow;
    o.x += acc.x * invl; o.y += acc.y * invl;
    o.z += acc.z * invl; o.w += acc.w * invl;
    *(float4*)orow = o;
  }
  for (int pos = b; pos < e; pos++) {
    if (act && (lane % LPH) == 0) {
      float sv = sc[(size_t)pos * H + head];
      alpha[(size_t)eid_s[pos] * H + head] = __expf(sv - m) * invl;
    }
  }
}

// ---------------- misc dense kernels ----------------

__global__ __launch_bounds__(256) void ln_relu(
    const float* __restrict__ in, const float* __restrict__ g,
    const float* __restrict__ b, float* __restrict__ o, int N) {
  int w = (blockIdx.x * 256 + threadIdx.x) >> 6;
  int lane = threadIdx.x & 63;
  if (w >= N) return;
  float4 x = *(const float4*)(in + (size_t)w * 256 + lane * 4);
  float s = x.x + x.y + x.z + x.w;
  float s2 = x.x * x.x + x.y * x.y + x.z * x.z + x.w * x.w;
  for (int m = 1; m < 64; m <<= 1) { s += __shfl_xor(s, m, 64); s2 += __shfl_xor(s2, m, 64); }
  float mu = s * (1.0f / 256.0f);
  float var = s2 * (1.0f / 256.0f) - mu * mu;
  float inv = rsqrtf(var + 1e-5f);
  float4 gv = *(const float4*)(g + lane * 4);
  float4 bv = *(const float4*)(b + lane * 4);
  float4 y;
  y.x = fmaxf(fmaf((x.x - mu) * inv, gv.x, bv.x), 0.f);
  y.y = fmaxf(fmaf((x.y - mu) * inv, gv.y, bv.y), 0.f);
  y.z = fmaxf(fmaf((x.z - mu) * inv, gv.z, bv.z), 0.f);
  y.w = fmaxf(fmaf((x.w - mu) * inv, gv.w, bv.w), 0.f);
  *(float4*)(o + (size_t)w * 256 + lane * 4) = y;
}

// segmented residual+pool: batch is sorted; one block owns R contiguous rows,
// one thread per column, flush one atomic per (segment, column).
__global__ __launch_bounds__(192) void resid_pool2(
    const float* __restrict__ x, const float* __restrict__ x3,
    const int* __restrict__ batch, float* __restrict__ pooled,
    float* __restrict__ cnt, int N, int R) {
  int col = threadIdx.x;  // 0..191
  int r0 = blockIdx.x * R;
  int r1 = min(r0 + R, N);
  if (r0 >= N) return;
  float acc = 0.f;
  int cur = batch[r0];
  int run = 0;
  for (int r = r0; r < r1; r++) {
    int b = batch[r];
    if (b != cur) {
      atomicAdd(&pooled[cur * 192 + col], acc);
      if (col == 0) atomicAdd(&cnt[cur], (float)run);
      acc = 0.f; run = 0; cur = b;
    }
    size_t i = (size_t)r * 192 + col;
    acc += x[i] + fmaxf(x3[i], 0.f);
    run++;
  }
  atomicAdd(&pooled[cur * 192 + col], acc);
  if (col == 0) atomicAdd(&cnt[cur], (float)run);
}

__global__ __launch_bounds__(64) void head_mlp(
    const float* __restrict__ pooled, const float* __restrict__ cnt,
    const float* __restrict__ fc1w, const float* __restrict__ fc1b,
    const float* __restrict__ fc2w, const float* __restrict__ fc2b,
    float* __restrict__ logits) {
  int b = blockIdx.x;
  int t = threadIdx.x;
  __shared__ float p[192];
  __shared__ float hbuf[32];
  float inv = 1.0f / fmaxf(cnt[b], 1.0f);
  for (int i = t; i < 192; i += 64) p[i] = pooled[b * 192 + i] * inv;
  __syncthreads();
  if (t < 32) {
    float acc = fc1b[t];
    for (int i = 0; i < 192; i++) acc = fmaf(p[i], fc1w[i * 32 + t], acc);
    hbuf[t] = fmaxf(acc, 0.f);
  }
  __syncthreads();
  if (t < 2) {
    float acc = fc2b[t];
    for (int j = 0; j < 32; j++) acc = fmaf(hbuf[j], fc2w[j * 2 + t], acc);
    logits[b * 2 + t] = acc;
  }
}

static inline int divup(int a, int b) { return (a + b - 1) / b; }

extern "C" void kernel_launch(void* const* d_in, const int* in_sizes, int n_in,
                              void* d_out, int out_size, void* d_ws, size_t ws_size,
                              hipStream_t stream) {
  const int N = 20000, E = 320000, B = 64;
  const float* x     = (const float*)d_in[0];
  const int*   ei    = (const int*)d_in[1];
  const float* eattr = (const float*)d_in[2];
  const int*   batch = (const int*)d_in[3];
  const int* srcp = ei;
  const int* dstp = ei + E;

  const float* Wq[3]; const float* bq[3]; const float* Wk[3]; const float* bk[3];
  const float* Wv[3]; const float* bv[3]; const float* We[3]; const float* Ws[3];
  const float* bs[3];
  for (int l = 0; l < 3; l++) {
    int base = 4 + l * 9;
    Wq[l] = (const float*)d_in[base + 0]; bq[l] = (const float*)d_in[base + 1];
    Wk[l] = (const float*)d_in[base + 2]; bk[l] = (const float*)d_in[base + 3];
    Wv[l] = (const float*)d_in[base + 4]; bv[l] = (const float*)d_in[base + 5];
    We[l] = (const float*)d_in[base + 6];
    Ws[l] = (const float*)d_in[base + 7]; bs[l] = (const float*)d_in[base + 8];
  }
  const float* g1  = (const float*)d_in[31]; const float* be1 = (const float*)d_in[32];
  const float* g2  = (const float*)d_in[33]; const float* be2 = (const float*)d_in[34];
  const float* fc1w = (const float*)d_in[35]; const float* fc1b = (const float*)d_in[36];
  const float* fc2w = (const float*)d_in[37]; const float* fc2b = (const float*)d_in[38];

  float* out = (float*)d_out;
  float* logits = out;
  float* a1 = out + 128;
  float* a2 = a1 + (size_t)E * 4;
  float* a3 = a2 + (size_t)E * 4;

  float* ws = (float*)d_ws;
  size_t o = 0;
  float* qb = ws + o; o += (size_t)N * 256;
  float* kb = ws + o; o += (size_t)N * 256;
  float* vb = ws + o; o += (size_t)N * 256;
  float* xa = ws + o; o += (size_t)N * 256;
  float* xb = ws + o; o += (size_t)N * 256;
  float* sc = ws + o; o += (size_t)E * 6;
  int*   cntb  = (int*)(ws + o); o += N;
  int*   startb= (int*)(ws + o); o += N + 1;
  int*   offb  = (int*)(ws + o); o += N + 1;
  int*   src_s = (int*)(ws + o); o += E;
  float* ea_s  = ws + o; o += E;
  int*   eid_s = (int*)(ws + o); o += E;
  float* pooled = ws + o; o += (size_t)B * 192;
  float* cnt    = ws + o; o += B;
  // bf16 split buffers (uint16), allocated in float units
  unsigned short* Ah = (unsigned short*)(ws + o); o += (size_t)N * 128;  // N*256 u16
  unsigned short* Al = (unsigned short*)(ws + o); o += (size_t)N * 128;
  unsigned short* Wh12 = (unsigned short*)(ws + o); o += (size_t)12 * 32768;  // 12*65536 u16
  unsigned short* Wl12 = (unsigned short*)(ws + o); o += (size_t)12 * 32768;

  dim3 blk(256);

  // ---- weight conversion (transpose + hi/lo split), all 12 up front ----
  struct LayerCfg { int K, M; float scale; };
  LayerCfg cfg[3] = {
    {192, 256, 0.125f},
    {256, 256, 0.125f},
    {256, 192, 0.1767766952966369f},
  };
  const float* Wmats[12];
  for (int l = 0; l < 3; l++) {
    Wmats[l * 4 + 0] = Wq[l]; Wmats[l * 4 + 1] = Wk[l];
    Wmats[l * 4 + 2] = Wv[l]; Wmats[l * 4 + 3] = Ws[l];
  }
  for (int i = 0; i < 12; i++) {
    int l = i / 4;
    int KM = cfg[l].K * cfg[l].M;
    cvt_w<<<divup(KM, 256), blk, 0, stream>>>(Wmats[i], Wh12 + (size_t)i * 65536,
                                              Wl12 + (size_t)i * 65536, cfg[l].K, cfg[l].M);
  }

  // ---- counting sort of edges by dst ----
  fill_i32<<<divup(N, 256), blk, 0, stream>>>(cntb, 0, N);
  hist_dst<<<divup(E, 256), blk, 0, stream>>>(dstp, cntb, E);
  scan_hist<<<1, dim3(1024), 0, stream>>>(cntb, startb, offb, N);
  scatter_edges<<<divup(E, 256), blk, 0, stream>>>(srcp, dstp, eattr, offb,
                                                  src_s, ea_s, eid_s, E);

  const float* lin_in[3]  = {x, xa, xb};
  float*       lay_out[3] = {xa, xb, xa};
  float*       alpha_out[3] = {a1, a2, a3};

  for (int l = 0; l < 3; l++) {
    int K = cfg[l].K, M = cfg[l].M;
    cvt_split<<<divup(N * K, 256), blk, 0, stream>>>(lin_in[l], Ah, Al, N * K);
    GemmArgs ga;
    float* outs[4] = {qb, kb, vb, lay_out[l]};
    const float* biases[4] = {bq[l], bk[l], bv[l], bs[l]};
    for (int z = 0; z < 4; z++) {
      ga.Wh[z] = Wh12 + (size_t)(l * 4 + z) * 65536;
      ga.Wl[z] = Wl12 + (size_t)(l * 4 + z) * 65536;
      ga.bias[z] = biases[z];
      ga.out[z] = outs[z];
    }
    dim3 gg(M / 64, divup(N, 256), 4);
    gemm4_mfma<<<gg, blk, 0, stream>>>(Ah, Al, ga, N, K, M);

    dim3 gat(divup(N * 64, 256));
    if (l < 2) {
      attn_fused<4, 16><<<gat, blk, 0, stream>>>(qb, kb, vb, We[l], startb, src_s,
                                                 ea_s, eid_s, sc, lay_out[l],
                                                 alpha_out[l], N, cfg[l].scale);
    } else {
      attn_fused<6, 8><<<gat, blk, 0, stream>>>(qb, kb, vb, We[l], startb, src_s,
                                                ea_s, eid_s, sc, lay_out[l],
                                                alpha_out[l], N, cfg[l].scale);
    }
    if (l == 0) ln_relu<<<divup(N, 4), blk, 0, stream>>>(xa, g1, be1, xa, N);
    if (l == 1) ln_relu<<<divup(N, 4), blk, 0, stream>>>(xb, g2, be2, xb, N);
  }

  fill_i32<<<divup(B * 192 + B, 256), blk, 0, stream>>>((int*)pooled, 0, B * 192 + B);
  resid_pool2<<<divup(N, 128), dim3(192), 0, stream>>>(x, xa, batch, pooled, cnt, N, 128);
  head_mlp<<<B, dim3(64), 0, stream>>>(pooled, cnt, fc1w, fc1b, fc2w, fc2b, logits);
}